// Round 5
// baseline (405.801 us; speedup 1.0000x reference)
//
#include <hip/hip_runtime.h>

// Geometry
constexpr int   NX    = 96;
constexpr int   SY    = 96;
constexpr int   SZ    = 96 * 96;
constexpr int   VOL   = 96 * 96 * 96;
constexpr int   NT_IN = 8;
constexpr int   NT    = 7;
constexpr int   NB    = 2;
constexpr int   NTOT  = NB * NT * VOL;   // 12386304
constexpr int   TX    = 24;              // threads along x, 4 floats each
constexpr int   YG    = 8;               // y rows per block
constexpr int   BLK   = TX * YG;         // 192 threads = 3 waves
constexpr int   ZC    = 12;              // z planes marched per block
constexpr int   NZC   = NX / ZC;         // 8
constexpr int   NYG   = NX / YG;         // 12
constexpr int   NBLK  = NB * NT * NYG * NZC; // 1344 blocks = 4032 waves (one residency wave @4/SIMD)

constexpr float DTI    = 100.0f;
constexpr float INVH   = 10.0f;
constexpr float INV2H  = 5.0f;
constexpr float INV2H2 = 50.0f;
constexpr float INV4H2 = 25.0f;
constexpr float D_EFF  = 0.001f;

__device__ __forceinline__ void ld4(float* d, const float* __restrict__ p) {
    *(float4*)d = *(const float4*)p;
}

// 5-tap weights for gradient(gradient(.)) over taps (m2,m1,c,p1,p2), axis size 96.
// Weight-0 taps multiply clamped (but finite) loads -> contribute exactly 0.
__device__ __forceinline__ void wts5(int i, float* w) {
    if (i == 0)       { w[0]=0.f;     w[1]=0.f;          w[2]=INV2H2;       w[3]=-2.f*INV2H2; w[4]=INV2H2; }
    else if (i == 1)  { w[0]=0.f;     w[1]=2.f*INV4H2;   w[2]=-3.f*INV4H2;  w[3]=0.f;         w[4]=INV4H2; }
    else if (i == 94) { w[0]=INV4H2;  w[1]=0.f;          w[2]=-3.f*INV4H2;  w[3]=2.f*INV4H2;  w[4]=0.f;    }
    else if (i == 95) { w[0]=INV2H2;  w[1]=-2.f*INV2H2;  w[2]=INV2H2;       w[3]=0.f;         w[4]=0.f;    }
    else              { w[0]=INV4H2;  w[1]=0.f;          w[2]=-2.f*INV4H2;  w[3]=0.f;         w[4]=INV4H2; }
}

__global__ __launch_bounds__(BLK, 4) void resid_kernel(
    const float* __restrict__ c_pred, const float* __restrict__ u_future,
    const float* __restrict__ mask, float* __restrict__ partial) {
    const int tid = threadIdx.x;
    const int tx  = tid % TX;        // 0..23
    const int ty  = tid / TX;        // 0..7

    // Block decode (compile-time divisors)
    int bid = blockIdx.x;
    const int yg = bid % NYG;  bid /= NYG;
    const int zc = bid % NZC;  bid /= NZC;
    const int t  = bid % NT;
    const int b  = bid / NT;
    const int z0 = zc * ZC;
    const int y  = yg * YG + ty;
    const int xb = tx * 4;

    // Region bases (uniform)
    const float* ct   = c_pred + (size_t)(b * NT_IN + t + 1) * VOL;
    const float* ctm1 = ct - VOL;
    const float* ux   = u_future + (size_t)((b * NT_IN + t + 1) * 3) * VOL;
    const float* uyb  = ux + VOL;
    const float* uzb  = uyb + VOL;
    const float* mkb  = mask + (size_t)b * VOL;

    // Per-thread voffsets (loop-invariant)
    const int vc   = y * SY + xb;
    const int vxl  = vc + ((tx > 0)      ? -4 : 0);
    const int vxr  = vc + ((tx < TX - 1) ?  4 : 0);
    const int vym1 = ((y > 0)  ? y - 1 : 0)  * SY + xb;
    const int vyp1 = ((y < 95) ? y + 1 : 95) * SY + xb;
    const int vym2 = ((y > 1)  ? y - 2 : 0)  * SY + xb;
    const int vyp2 = ((y < 94) ? y + 2 : 95) * SY + xb;

    float wy[5];
    wts5(y, wy);
    const float fy = (y == 0 || y == 95) ? INVH : INV2H;

    // Prime rotating c-plane state (clamped at the low end)
    const int zm2 = (z0 >= 2) ? z0 - 2 : 0;
    const int zm1 = (z0 >= 1) ? z0 - 1 : 0;
    float czm2[4], czm1[4], cc[4], czp1[4], czp2[4];
    ld4(czm2, ct + zm2 * SZ + vc);
    ld4(czm1, ct + zm1 * SZ + vc);
    ld4(cc,   ct + z0 * SZ + vc);
    ld4(czp1, ct + (z0 + 1) * SZ + vc);

    float acc = 0.0f;

    #pragma unroll 2
    for (int iz = 0; iz < ZC; ++iz) {
        const int z    = z0 + iz;              // uniform
        const int zoff = z * SZ;
        const int zp2  = (z < 94) ? z + 2 : 95;
        const int zp1o = ((z < 95) ? z + 1 : 95) * SZ;
        const int zm1o = ((z > 0)  ? z - 1 : 0) * SZ;

        // 16 independent ld4 (SGPR plane base + invariant voffset)
        float cL[4], cR[4], cym1[4], cyp1[4], cym2[4], cyp2[4];
        float uxm[4], uxp[4], uym[4], uyp[4], uzL[4], uzC[4], uzR[4], cm1[4], mv[4];
        ld4(czp2, ct + zp2 * SZ + vc);
        ld4(uxm,  ux + zm1o + vc);
        ld4(uxp,  ux + zp1o + vc);
        ld4(cL,   ct + zoff + vxl);
        ld4(cR,   ct + zoff + vxr);
        ld4(cym1, ct + zoff + vym1);
        ld4(cyp1, ct + zoff + vyp1);
        ld4(cym2, ct + zoff + vym2);
        ld4(cyp2, ct + zoff + vyp2);
        ld4(uym,  uyb + zoff + vym1);
        ld4(uyp,  uyb + zoff + vyp1);
        ld4(uzL,  uzb + zoff + vxl);
        ld4(uzC,  uzb + zoff + vc);
        ld4(uzR,  uzb + zoff + vxr);
        ld4(cm1,  ctm1 + zoff + vc);
        ld4(mv,   mkb + zoff + vc);

        // Per-step uniform z weights / factor
        float wz[5];
        wts5(z, wz);
        const float fz = (z == 0 || z == 95) ? INVH : INV2H;

        // x windows (static indexing only): ax[k] = c at x = xb-2+k
        float ax[8], uzw[8];
        ax[0] = cL[2];  ax[1] = cL[3];
        ax[2] = cc[0];  ax[3] = cc[1];  ax[4] = cc[2];  ax[5] = cc[3];
        ax[6] = cR[0];  ax[7] = cR[1];
        uzw[0] = uzL[2]; uzw[1] = uzL[3];
        uzw[2] = uzC[0]; uzw[3] = uzC[1]; uzw[4] = uzC[2]; uzw[5] = uzC[3];
        uzw[6] = uzR[0]; uzw[7] = uzR[1];
        float P[7];
        #pragma unroll
        for (int k = 1; k <= 6; ++k) P[k] = uzw[k] * ax[k];

        // x-laplacian: uniform interior weights; rare divergent patch at x edges
        float lx[4];
        #pragma unroll
        for (int j = 0; j < 4; ++j)
            lx[j] = (ax[j + 4] - 2.0f * ax[j + 2] + ax[j]) * INV4H2;
        if (tx == 0) {             // x = 0,1 (ax[2]=c0, ax[3]=c1, ...)
            lx[0] = (ax[4] - 2.0f * ax[3] + ax[2]) * INV2H2;
            lx[1] = (ax[5] - 3.0f * ax[3] + 2.0f * ax[2]) * INV4H2;
        }
        if (tx == TX - 1) {        // x = 94,95 (ax[4]=c94, ax[5]=c95)
            lx[2] = (2.0f * ax[5] - 3.0f * ax[4] + ax[2]) * INV4H2;
            lx[3] = (ax[5] - 2.0f * ax[4] + ax[3]) * INV2H2;
        }

        #pragma unroll
        for (int j = 0; j < 4; ++j) {
            const float dc  = (cc[j] - cm1[j]) * DTI;
            const float fzv = (uxp[j] * czp1[j] - uxm[j] * czm1[j]) * fz;
            const float fyv = (uyp[j] * cyp1[j] - uym[j] * cym1[j]) * fy;
            float fxv = (P[j + 3] - P[j + 1]) * INV2H;
            if (j == 0) fxv = (xb == 0)  ? (P[3] - P[2]) * INVH : fxv;
            if (j == 3) fxv = (xb == 92) ? (P[5] - P[4]) * INVH : fxv;

            float lap = wz[0]*czm2[j] + wz[1]*czm1[j] + wz[2]*cc[j] + wz[3]*czp1[j] + wz[4]*czp2[j];
            lap += wy[0]*cym2[j] + wy[1]*cym1[j] + wy[2]*cc[j] + wy[3]*cyp1[j] + wy[4]*cyp2[j];
            lap += lx[j];

            const float r = (dc + fzv + fyv + fxv - D_EFF * lap) * mv[j];
            acc += r * r;
        }

        // Rotate c-plane state
        #pragma unroll
        for (int q = 0; q < 4; ++q) {
            czm2[q] = czm1[q]; czm1[q] = cc[q]; cc[q] = czp1[q]; czp1[q] = czp2[q];
        }
    }

    // 3-wave block reduction
    #pragma unroll
    for (int off = 32; off > 0; off >>= 1) acc += __shfl_down(acc, off, 64);
    __shared__ float smem[3];
    const int lane = tid & 63, wid = tid >> 6;
    if (lane == 0) smem[wid] = acc;
    __syncthreads();
    if (tid == 0) partial[blockIdx.x] = smem[0] + smem[1] + smem[2];
}

__global__ __launch_bounds__(256) void final_reduce(
    const float* __restrict__ partial, int n, float* __restrict__ out) {
    float s = 0.0f;
    for (int i = threadIdx.x; i < n; i += 256) s += partial[i];
    #pragma unroll
    for (int off = 32; off > 0; off >>= 1) s += __shfl_down(s, off, 64);
    __shared__ float smem[4];
    const int lane = threadIdx.x & 63, wid = threadIdx.x >> 6;
    if (lane == 0) smem[wid] = s;
    __syncthreads();
    if (threadIdx.x == 0)
        out[0] = (smem[0] + smem[1] + smem[2] + smem[3]) * (1.0f / (float)NTOT);
}

extern "C" void kernel_launch(void* const* d_in, const int* in_sizes, int n_in,
                              void* d_out, int out_size, void* d_ws, size_t ws_size,
                              hipStream_t stream) {
    const float* c_pred   = (const float*)d_in[0];
    const float* u_future = (const float*)d_in[1];
    const float* mask     = (const float*)d_in[2];
    float* out     = (float*)d_out;
    float* partial = (float*)d_ws;

    resid_kernel<<<NBLK, BLK, 0, stream>>>(c_pred, u_future, mask, partial);
    final_reduce<<<1, 256, 0, stream>>>(partial, NBLK, out);
}

// Round 6
// 283.190 us; speedup vs baseline: 1.4330x; 1.4330x over previous
//
#include <hip/hip_runtime.h>

// Geometry
constexpr int   NX    = 96;
constexpr int   SY    = 96;
constexpr int   SZ    = 96 * 96;
constexpr int   VOL   = 96 * 96 * 96;
constexpr int   NT_IN = 8;
constexpr int   NT    = 7;
constexpr int   NB    = 2;
constexpr int   NTOT  = NB * NT * VOL;   // 12386304
constexpr int   BLKT  = 256;             // threads = 4 waves (even across SIMDs)
constexpr int   SPAN  = BLKT * 4;        // 1024 floats of a plane per block
constexpr int   NSP   = SZ / SPAN;       // 9 spans per 9216-float plane
constexpr int   ZC    = 12;              // z planes marched per block
constexpr int   NZC   = NX / ZC;         // 8
constexpr int   NBLK  = NB * NT * NZC * NSP; // 1008 blocks = 4032 waves

constexpr float DTI    = 100.0f;
constexpr float INVH   = 10.0f;
constexpr float INV2H  = 5.0f;
constexpr float INV2H2 = 50.0f;
constexpr float INV4H2 = 25.0f;
constexpr float D_EFF  = 0.001f;

__device__ __forceinline__ void ld4(float* d, const float* __restrict__ p) {
    *(float4*)d = *(const float4*)p;
}

// 5-tap weights for gradient(gradient(.)) over taps (m2,m1,c,p1,p2), axis size 96.
// Zero-weight taps multiply clamped (finite) loads -> contribute exactly 0.
__device__ __forceinline__ void wts5(int i, float* w) {
    if (i == 0)       { w[0]=0.f;     w[1]=0.f;          w[2]=INV2H2;       w[3]=-2.f*INV2H2; w[4]=INV2H2; }
    else if (i == 1)  { w[0]=0.f;     w[1]=2.f*INV4H2;   w[2]=-3.f*INV4H2;  w[3]=0.f;         w[4]=INV4H2; }
    else if (i == 94) { w[0]=INV4H2;  w[1]=0.f;          w[2]=-3.f*INV4H2;  w[3]=2.f*INV4H2;  w[4]=0.f;    }
    else if (i == 95) { w[0]=INV2H2;  w[1]=-2.f*INV2H2;  w[2]=INV2H2;       w[3]=0.f;         w[4]=0.f;    }
    else              { w[0]=INV4H2;  w[1]=0.f;          w[2]=-2.f*INV4H2;  w[3]=0.f;         w[4]=INV4H2; }
}

__global__ __launch_bounds__(BLKT, 4) void resid_kernel(
    const float* __restrict__ c_pred, const float* __restrict__ u_future,
    const float* __restrict__ mask, float* __restrict__ partial) {
    const int tid = threadIdx.x;

    // Block decode (compile-time divisors)
    int bid = blockIdx.x;
    const int sp = bid % NSP;  bid /= NSP;
    const int zc = bid % NZC;  bid /= NZC;
    const int t  = bid % NT;
    const int b  = bid / NT;
    const int z0 = zc * ZC;

    // Flat in-plane position: each thread owns 4 consecutive x (one float4,
    // never straddles a row since 96 % 4 == 0).
    const int q  = sp * SPAN + tid * 4;  // 0..9215
    const int y  = q / SY;
    const int xb = q - y * SY;           // multiple of 4

    // Region bases (uniform -> SGPR)
    const float* ct   = c_pred + (size_t)(b * NT_IN + t + 1) * VOL;
    const float* ctm1 = ct - VOL;
    const float* uxB  = u_future + (size_t)((b * NT_IN + t + 1) * 3) * VOL;
    const float* uyB  = uxB + VOL;
    const float* uzB  = uyB + VOL;
    const float* mkB  = mask + (size_t)b * VOL;

    // Per-thread in-plane voffsets (loop-invariant)
    const int vc   = q;
    const int vxl  = q + ((xb > 0)  ? -4 : 0);
    const int vxr  = q + ((xb < 92) ?  4 : 0);
    const int vym1 = ((y > 0)  ? y - 1 : 0)  * SY + xb;
    const int vyp1 = ((y < 95) ? y + 1 : 95) * SY + xb;
    const int vym2 = ((y > 1)  ? y - 2 : 0)  * SY + xb;
    const int vyp2 = ((y < 94) ? y + 2 : 95) * SY + xb;

    float wy[5];
    wts5(y, wy);
    const float fy = (y == 0 || y == 95) ? INVH : INV2H;

    float acc = 0.0f;

    #pragma unroll 1
    for (int iz = 0; iz < ZC; ++iz) {
        const int z = z0 + iz;                         // uniform
        // Uniform plane bases (SALU adds)
        const float* cz   = ct + z * SZ;
        const float* czm1p= ct + ((z > 0)  ? z - 1 : 0)  * SZ;
        const float* czp1p= ct + ((z < 95) ? z + 1 : 95) * SZ;
        const float* czm2p= ct + ((z > 1)  ? z - 2 : 0)  * SZ;
        const float* czp2p= ct + ((z < 94) ? z + 2 : 95) * SZ;
        const float* uxm_p= uxB + ((z > 0)  ? z - 1 : 0)  * SZ;
        const float* uxp_p= uxB + ((z < 95) ? z + 1 : 95) * SZ;
        const float* uyz  = uyB + z * SZ;
        const float* uzz  = uzB + z * SZ;
        const float* cm1p = ctm1 + z * SZ;
        const float* mkz  = mkB + z * SZ;

        // 20 independent ld4 (SGPR base + invariant voffset)
        float cc[4], czm1[4], czp1[4], czm2[4], czp2[4];
        float cL[4], cR[4], cym1[4], cyp1[4], cym2[4], cyp2[4];
        float uxm[4], uxp[4], uym[4], uyp[4], uzL[4], uzC[4], uzR[4];
        float cm1[4], mv[4];
        ld4(cc,   cz + vc);
        ld4(czm1, czm1p + vc);
        ld4(czp1, czp1p + vc);
        ld4(czm2, czm2p + vc);
        ld4(czp2, czp2p + vc);
        ld4(cL,   cz + vxl);
        ld4(cR,   cz + vxr);
        ld4(cym1, cz + vym1);
        ld4(cyp1, cz + vyp1);
        ld4(cym2, cz + vym2);
        ld4(cyp2, cz + vyp2);
        ld4(uxm,  uxm_p + vc);
        ld4(uxp,  uxp_p + vc);
        ld4(uym,  uyz + vym1);
        ld4(uyp,  uyz + vyp1);
        ld4(uzL,  uzz + vxl);
        ld4(uzC,  uzz + vc);
        ld4(uzR,  uzz + vxr);
        ld4(cm1,  cm1p + vc);
        ld4(mv,   mkz + vc);

        // Per-step uniform z weights / factor
        float wz[5];
        wts5(z, wz);
        const float fz = (z == 0 || z == 95) ? INVH : INV2H;

        // x windows (static indexing only): ax[k] = c at x = xb-2+k
        float ax[8], uzw[8];
        ax[0] = cL[2];  ax[1] = cL[3];
        ax[2] = cc[0];  ax[3] = cc[1];  ax[4] = cc[2];  ax[5] = cc[3];
        ax[6] = cR[0];  ax[7] = cR[1];
        uzw[0] = uzL[2]; uzw[1] = uzL[3];
        uzw[2] = uzC[0]; uzw[3] = uzC[1]; uzw[4] = uzC[2]; uzw[5] = uzC[3];
        uzw[6] = uzR[0]; uzw[7] = uzR[1];
        float P[7];
        #pragma unroll
        for (int k = 1; k <= 6; ++k) P[k] = uzw[k] * ax[k];

        // x-laplacian: uniform interior weights; rare per-thread edge patch
        float lx[4];
        #pragma unroll
        for (int j = 0; j < 4; ++j)
            lx[j] = (ax[j + 4] - 2.0f * ax[j + 2] + ax[j]) * INV4H2;
        if (xb == 0) {        // x = 0,1
            lx[0] = (ax[4] - 2.0f * ax[3] + ax[2]) * INV2H2;
            lx[1] = (ax[5] - 3.0f * ax[3] + 2.0f * ax[2]) * INV4H2;
        }
        if (xb == 92) {       // x = 94,95
            lx[2] = (2.0f * ax[5] - 3.0f * ax[4] + ax[2]) * INV4H2;
            lx[3] = (ax[5] - 2.0f * ax[4] + ax[3]) * INV2H2;
        }

        #pragma unroll
        for (int j = 0; j < 4; ++j) {
            const float dc  = (cc[j] - cm1[j]) * DTI;
            const float fzv = (uxp[j] * czp1[j] - uxm[j] * czm1[j]) * fz;
            const float fyv = (uyp[j] * cyp1[j] - uym[j] * cym1[j]) * fy;
            float fxv = (P[j + 3] - P[j + 1]) * INV2H;
            if (j == 0 && xb == 0)  fxv = (P[3] - P[2]) * INVH;
            if (j == 3 && xb == 92) fxv = (P[5] - P[4]) * INVH;

            float lap = wz[0]*czm2[j] + wz[1]*czm1[j] + wz[2]*cc[j] + wz[3]*czp1[j] + wz[4]*czp2[j];
            lap += wy[0]*cym2[j] + wy[1]*cym1[j] + wy[2]*cc[j] + wy[3]*cyp1[j] + wy[4]*cyp2[j];
            lap += lx[j];

            const float r = (dc + fzv + fyv + fxv - D_EFF * lap) * mv[j];
            acc += r * r;
        }
    }

    // 4-wave block reduction
    #pragma unroll
    for (int off = 32; off > 0; off >>= 1) acc += __shfl_down(acc, off, 64);
    __shared__ float smem[4];
    const int lane = tid & 63, wid = tid >> 6;
    if (lane == 0) smem[wid] = acc;
    __syncthreads();
    if (tid == 0) partial[blockIdx.x] = smem[0] + smem[1] + smem[2] + smem[3];
}

__global__ __launch_bounds__(256) void final_reduce(
    const float* __restrict__ partial, int n, float* __restrict__ out) {
    float s = 0.0f;
    for (int i = threadIdx.x; i < n; i += 256) s += partial[i];
    #pragma unroll
    for (int off = 32; off > 0; off >>= 1) s += __shfl_down(s, off, 64);
    __shared__ float smem[4];
    const int lane = threadIdx.x & 63, wid = threadIdx.x >> 6;
    if (lane == 0) smem[wid] = s;
    __syncthreads();
    if (threadIdx.x == 0)
        out[0] = (smem[0] + smem[1] + smem[2] + smem[3]) * (1.0f / (float)NTOT);
}

extern "C" void kernel_launch(void* const* d_in, const int* in_sizes, int n_in,
                              void* d_out, int out_size, void* d_ws, size_t ws_size,
                              hipStream_t stream) {
    const float* c_pred   = (const float*)d_in[0];
    const float* u_future = (const float*)d_in[1];
    const float* mask     = (const float*)d_in[2];
    float* out     = (float*)d_out;
    float* partial = (float*)d_ws;

    resid_kernel<<<NBLK, BLKT, 0, stream>>>(c_pred, u_future, mask, partial);
    final_reduce<<<1, 256, 0, stream>>>(partial, NBLK, out);
}